// Round 5
// baseline (11514.904 us; speedup 1.0000x reference)
//
#include <hip/hip_runtime.h>
#include <cstdint>
#include <cstddef>

#define SEQ 4096
#define HID 512
#define NTHETA 5
#define NWRK 8                  // worker blocks (all on one XCD)
#define SENT_BITS 0x40000000u   // 2.0f — |tanh| < 1, so never a real h value

__device__ __forceinline__ float tanh_fast(float x) {
  x = fminf(fmaxf(x, -20.0f), 20.0f);
  const float e = __expf(2.0f * x);
  return (e - 1.0f) / (e + 1.0f);
}

// L1-bypass load (sc0): sees same-XCD L2 updates without paying L3 latency.
__device__ __forceinline__ unsigned load_sc0(const unsigned* p) {
  unsigned u;
  asm volatile("global_load_dword %0, %1, off sc0\n\ts_waitcnt vmcnt(0)"
               : "=v"(u) : "v"(p) : "memory");
  return u;
}

// C[4096,512] = act(A[4096,K] @ W[512,K]^T + bias + noise_plane)
__global__ __launch_bounds__(256) void gemm_bias_noise(
    const float* __restrict__ A, const float* __restrict__ W,
    const float* __restrict__ bias, const float* __restrict__ noise,
    float* __restrict__ C, int K, int doTanh)
{
  const int N = HID;
  const int bm = blockIdx.y, bn = blockIdx.x;
  const int tid = threadIdx.x;
  const int tx = tid & 15, ty = tid >> 4;
  const int row0 = bm * 64, col0 = bn * 64;
  __shared__ float As[16][68];
  __shared__ float Ws[16][68];
  float acc[4][4] = {{0.f, 0.f, 0.f, 0.f}, {0.f, 0.f, 0.f, 0.f},
                     {0.f, 0.f, 0.f, 0.f}, {0.f, 0.f, 0.f, 0.f}};
  const int lrow = tid >> 2, lkq = tid & 3;
  for (int kt = 0; kt < K; kt += 16) {
    const float4 av = *(const float4*)&A[(size_t)(row0 + lrow) * K + kt + lkq * 4];
    const float4 wv = *(const float4*)&W[(size_t)(col0 + lrow) * K + kt + lkq * 4];
    __syncthreads();
    As[lkq * 4 + 0][lrow] = av.x; As[lkq * 4 + 1][lrow] = av.y;
    As[lkq * 4 + 2][lrow] = av.z; As[lkq * 4 + 3][lrow] = av.w;
    Ws[lkq * 4 + 0][lrow] = wv.x; Ws[lkq * 4 + 1][lrow] = wv.y;
    Ws[lkq * 4 + 2][lrow] = wv.z; Ws[lkq * 4 + 3][lrow] = wv.w;
    __syncthreads();
#pragma unroll
    for (int k = 0; k < 16; ++k) {
      const float4 a = *(const float4*)&As[k][ty * 4];
      const float4 bq = *(const float4*)&Ws[k][tx * 4];
      const float a4[4] = {a.x, a.y, a.z, a.w};
      const float b4[4] = {bq.x, bq.y, bq.z, bq.w};
#pragma unroll
      for (int i = 0; i < 4; ++i)
#pragma unroll
        for (int j = 0; j < 4; ++j)
          acc[i][j] = fmaf(a4[i], b4[j], acc[i][j]);
    }
  }
  const float4 bv = *(const float4*)&bias[col0 + tx * 4];
#pragma unroll
  for (int i = 0; i < 4; ++i) {
    const int row = row0 + ty * 4 + i;
    const float4 nv = *(const float4*)&noise[(size_t)row * N + col0 + tx * 4];
    float4 o;
    o.x = acc[i][0] + bv.x + nv.x;
    o.y = acc[i][1] + bv.y + nv.y;
    o.z = acc[i][2] + bv.z + nv.z;
    o.w = acc[i][3] + bv.w + nv.w;
    if (doTanh) {
      o.x = tanh_fast(o.x); o.y = tanh_fast(o.y);
      o.z = tanh_fast(o.z); o.w = tanh_fast(o.w);
    }
    *(float4*)&C[(size_t)row * N + col0 + tx * 4] = o;
  }
}

// Pre-fill the h-exchange buffer (= out plane 0) with the sentinel bits.
__global__ void fill_sentinel(uint4* __restrict__ p, int n4) {
  const int i = blockIdx.x * blockDim.x + threadIdx.x;
  if (i < n4) p[i] = make_uint4(SENT_BITS, SENT_BITS, SENT_BITS, SENT_BITS);
}

// Sequential scan h_t = tanh(drive_t + W_hh @ h_{t-1}), all workers on ONE XCD.
// Launch 256 blocks; each reads its XCC_ID and claims a per-XCD slot; first
// XCD to fill NWRK slots wins (CAS); all other blocks exit. Winning workers
// exchange h through L2 (producer: agent store = write-through; consumer:
// sc0 L1-bypass poll with periodic agent-scope backstop).
// Worker slot b owns rows [64b, 64b+64). Thread: r=tid>>4, s=tid&15;
// W[row, s+16k] (k<32) in regs; stride-16 LDS reads are bank-broadcast
// (conflict-free); 4-shuffle reduce; lane s==0 stores through out plane 0.
__global__ __launch_bounds__(1024) void recurrence(
    const float* __restrict__ Whh, const float* __restrict__ drive,
    const float* __restrict__ h0, unsigned* __restrict__ hexch,
    int* __restrict__ claim)   // claim[0..7]=per-XCD counters, claim[8]=chosen
{
  __shared__ int s_worker, s_slot;
  const int tid = threadIdx.x;

  if (tid == 0) {
    int xcd;
    asm volatile("s_getreg_b32 %0, hwreg(HW_REG_XCC_ID)" : "=s"(xcd));
    xcd &= 7;
    const int slot = atomicAdd(&claim[xcd], 1);          // device-scope
    if (slot == NWRK - 1) {
      int expected = 0;
      __hip_atomic_compare_exchange_strong(&claim[8], &expected, xcd + 1,
                                           __ATOMIC_RELAXED, __ATOMIC_RELAXED,
                                           __HIP_MEMORY_SCOPE_AGENT);
    }
    int ch;
    do {
      ch = __hip_atomic_load(&claim[8], __ATOMIC_RELAXED,
                             __HIP_MEMORY_SCOPE_AGENT);
    } while (ch == 0);
    s_worker = (ch == xcd + 1 && slot < NWRK) ? 1 : 0;
    s_slot = slot;
  }
  __syncthreads();
  if (!s_worker) return;

  const int base = s_slot * 64;
  const int r = tid >> 4;        // local row 0..63
  const int s = tid & 15;        // col slice 0..15
  const int row = base + r;

  __shared__ float hbuf[2][HID];

  // W slice -> 32 regs: cols s, s+16, ..., s+496 of row `row`
  float w[32];
#pragma unroll
  for (int k = 0; k < 32; ++k)
    w[k] = Whh[(size_t)row * HID + s + 16 * k];

  for (int t = 0; t < SEQ; ++t) {
    float drv = 0.f;
    if (s == 0) drv = drive[(size_t)t * HID + row];   // off critical path

    float* buf = hbuf[t & 1];
    if (tid < HID) {
      float v;
      if (t == 0) {
        v = h0[tid];
      } else {
        const unsigned* src = &hexch[(size_t)(t - 1) * HID + tid];
        unsigned u = load_sc0(src);
        int it = 0;
        while (u == SENT_BITS) {
          if ((++it & 15) == 0)
            u = __hip_atomic_load(src, __ATOMIC_RELAXED,
                                  __HIP_MEMORY_SCOPE_AGENT);  // backstop
          else
            u = load_sc0(src);                                // L2 fast path
        }
        v = __uint_as_float(u);
      }
      buf[tid] = v;
    }
    __syncthreads();   // buf[t&1] ready; skew <= 1 step => other buffer safe

    float a0 = 0.f, a1 = 0.f, a2 = 0.f, a3 = 0.f;
#pragma unroll
    for (int k = 0; k < 32; k += 4) {
      a0 = fmaf(w[k + 0], buf[s + 16 * (k + 0)], a0);
      a1 = fmaf(w[k + 1], buf[s + 16 * (k + 1)], a1);
      a2 = fmaf(w[k + 2], buf[s + 16 * (k + 2)], a2);
      a3 = fmaf(w[k + 3], buf[s + 16 * (k + 3)], a3);
    }
    float sum = (a0 + a1) + (a2 + a3);
#pragma unroll
    for (int off = 1; off < 16; off <<= 1)
      sum += __shfl_xor(sum, off, 64);

    if (s == 0) {
      const float y = tanh_fast(sum + drv);
      // agent store: write-through updates shared L2 (fast path) AND L3
      // (backstop + cross-kernel visibility).
      __hip_atomic_store(&hexch[(size_t)t * HID + row], __float_as_uint(y),
                         __ATOMIC_RELAXED, __HIP_MEMORY_SCOPE_AGENT);
    }
  }
}

__global__ void copy_final(const float* __restrict__ src, float* __restrict__ dst) {
  dst[threadIdx.x] = src[threadIdx.x];
}

extern "C" void kernel_launch(void* const* d_in, const int* in_sizes, int n_in,
                              void* d_out, int out_size, void* d_ws, size_t ws_size,
                              hipStream_t stream) {
  const float* input    = (const float*)d_in[0];
  const float* internal = (const float*)d_in[1];
  const float* state    = (const float*)d_in[2];
  const float* W_ih     = (const float*)d_in[3];
  const float* W_hh     = (const float*)d_in[4];
  const float* bias     = (const float*)d_in[5];
  float* out = (float*)d_out;

  const size_t plane = (size_t)SEQ * HID;
  // hexch IS out plane 0 (hs): prefilled with sentinel, every element
  // overwritten exactly once by the recurrence.
  unsigned* hexch = (unsigned*)out;
  float*    drive = out + 5 * plane;   // rewritten by theta-GEMM k=4 afterwards
  int*      claim = (int*)d_ws;        // claim[0..7] counters, claim[8] chosen

  hipMemsetAsync(d_ws, 0, 16 * sizeof(int), stream);
  fill_sentinel<<<(SEQ * HID / 4 + 255) / 256, 256, 0, stream>>>(
      (uint4*)hexch, SEQ * HID / 4);

  dim3 gg(HID / 64, SEQ / 64);
  // drive = x @ W_ih^T + b + internal[0]   (no tanh)
  gemm_bias_noise<<<gg, 256, 0, stream>>>(input, W_ih, bias, internal, drive,
                                          HID, 0);
  // hs (out plane 0, via same-XCD sentinel exchange); 256 blocks self-select
  recurrence<<<256, 1024, 0, stream>>>(W_hh, drive, state, hexch, claim);
  // theta rollouts: plane k -> plane k+1
  for (int k = 0; k < NTHETA; ++k) {
    gemm_bias_noise<<<gg, 256, 0, stream>>>(out + (size_t)k * plane, W_hh, bias,
                                            internal + (size_t)(k + 1) * plane,
                                            out + (size_t)(k + 1) * plane,
                                            HID, 1);
  }
  // final_state = hs[4095]
  copy_final<<<1, HID, 0, stream>>>(out + (size_t)4095 * HID, out + 6 * plane);
}

// Round 6
// 8842.329 us; speedup vs baseline: 1.3022x; 1.3022x over previous
//
#include <hip/hip_runtime.h>
#include <cstdint>
#include <cstddef>

#define SEQ 4096
#define HID 512
#define NTHETA 5
#define NBLK 8                  // 8 worker blocks (proven best population)
#define SENT_BITS 0x40000000u   // 2.0f — |tanh| < 1, so never a real h value

__device__ __forceinline__ float tanh_fast(float x) {
  x = fminf(fmaxf(x, -20.0f), 20.0f);
  const float e = __expf(2.0f * x);
  return (e - 1.0f) / (e + 1.0f);
}

// C[4096,512] = act(A[4096,K] @ W[512,K]^T + bias + noise_plane)
__global__ __launch_bounds__(256) void gemm_bias_noise(
    const float* __restrict__ A, const float* __restrict__ W,
    const float* __restrict__ bias, const float* __restrict__ noise,
    float* __restrict__ C, int K, int doTanh)
{
  const int N = HID;
  const int bm = blockIdx.y, bn = blockIdx.x;
  const int tid = threadIdx.x;
  const int tx = tid & 15, ty = tid >> 4;
  const int row0 = bm * 64, col0 = bn * 64;
  __shared__ float As[16][68];
  __shared__ float Ws[16][68];
  float acc[4][4] = {{0.f, 0.f, 0.f, 0.f}, {0.f, 0.f, 0.f, 0.f},
                     {0.f, 0.f, 0.f, 0.f}, {0.f, 0.f, 0.f, 0.f}};
  const int lrow = tid >> 2, lkq = tid & 3;
  for (int kt = 0; kt < K; kt += 16) {
    const float4 av = *(const float4*)&A[(size_t)(row0 + lrow) * K + kt + lkq * 4];
    const float4 wv = *(const float4*)&W[(size_t)(col0 + lrow) * K + kt + lkq * 4];
    __syncthreads();
    As[lkq * 4 + 0][lrow] = av.x; As[lkq * 4 + 1][lrow] = av.y;
    As[lkq * 4 + 2][lrow] = av.z; As[lkq * 4 + 3][lrow] = av.w;
    Ws[lkq * 4 + 0][lrow] = wv.x; Ws[lkq * 4 + 1][lrow] = wv.y;
    Ws[lkq * 4 + 2][lrow] = wv.z; Ws[lkq * 4 + 3][lrow] = wv.w;
    __syncthreads();
#pragma unroll
    for (int k = 0; k < 16; ++k) {
      const float4 a = *(const float4*)&As[k][ty * 4];
      const float4 bq = *(const float4*)&Ws[k][tx * 4];
      const float a4[4] = {a.x, a.y, a.z, a.w};
      const float b4[4] = {bq.x, bq.y, bq.z, bq.w};
#pragma unroll
      for (int i = 0; i < 4; ++i)
#pragma unroll
        for (int j = 0; j < 4; ++j)
          acc[i][j] = fmaf(a4[i], b4[j], acc[i][j]);
    }
  }
  const float4 bv = *(const float4*)&bias[col0 + tx * 4];
#pragma unroll
  for (int i = 0; i < 4; ++i) {
    const int row = row0 + ty * 4 + i;
    const float4 nv = *(const float4*)&noise[(size_t)row * N + col0 + tx * 4];
    float4 o;
    o.x = acc[i][0] + bv.x + nv.x;
    o.y = acc[i][1] + bv.y + nv.y;
    o.z = acc[i][2] + bv.z + nv.z;
    o.w = acc[i][3] + bv.w + nv.w;
    if (doTanh) {
      o.x = tanh_fast(o.x); o.y = tanh_fast(o.y);
      o.z = tanh_fast(o.z); o.w = tanh_fast(o.w);
    }
    *(float4*)&C[(size_t)row * N + col0 + tx * 4] = o;
  }
}

// Pre-fill the h-exchange buffer (= out plane 0) with the sentinel bits.
__global__ void fill_sentinel(uint4* __restrict__ p, int n4) {
  const int i = blockIdx.x * blockDim.x + threadIdx.x;
  if (i < n4) p[i] = make_uint4(SENT_BITS, SENT_BITS, SENT_BITS, SENT_BITS);
}

// Sequential scan h_t = tanh(drive_t + W_hh @ h_{t-1}).
// 8 blocks x 1024 thr; block owns 64 rows. Thread (r=tid>>4, s=tid&15) holds
// W[base+r, s+16k] (k<32) in regs. 512 loader threads poll one h value each
// (sentinel data-poll, agent scope, 1x redundancy) into double-buffered LDS;
// ONE barrier per step; stride-16 LDS reads are bank-broadcast (conflict-free,
// verified r4/r5: SQ_LDS_BANK_CONFLICT == 0); 4-shuffle reduce; lane s==0
// stores through the exchange plane (= out plane 0 / hs).
__global__ __launch_bounds__(1024) void recurrence(
    const float* __restrict__ Whh, const float* __restrict__ drive,
    const float* __restrict__ h0, unsigned* __restrict__ hexch)
{
  const int base = blockIdx.x * 64;
  const int tid = threadIdx.x;
  const int r = tid >> 4;        // local row 0..63
  const int s = tid & 15;        // col slice 0..15
  const int row = base + r;

  __shared__ float hbuf[2][HID];

  // W slice -> 32 regs: cols s, s+16, ..., s+496 of row `row`
  float w[32];
#pragma unroll
  for (int k = 0; k < 32; ++k)
    w[k] = Whh[(size_t)row * HID + s + 16 * k];

  for (int t = 0; t < SEQ; ++t) {
    float drv = 0.f;
    if (s == 0) drv = drive[(size_t)t * HID + row];   // issued before the spin

    float* buf = hbuf[t & 1];
    if (tid < HID) {
      float v;
      if (t == 0) {
        v = h0[tid];
      } else {
        const unsigned* src = &hexch[(size_t)(t - 1) * HID + tid];
        unsigned u;
        do {
          u = __hip_atomic_load(src, __ATOMIC_RELAXED,
                                __HIP_MEMORY_SCOPE_AGENT);
        } while (u == SENT_BITS);
        v = __uint_as_float(u);
      }
      buf[tid] = v;
    }
    __syncthreads();   // buf[t&1] ready; skew <= 1 step => other buffer safe

    float a0 = 0.f, a1 = 0.f, a2 = 0.f, a3 = 0.f;
#pragma unroll
    for (int k = 0; k < 32; k += 4) {
      a0 = fmaf(w[k + 0], buf[s + 16 * (k + 0)], a0);
      a1 = fmaf(w[k + 1], buf[s + 16 * (k + 1)], a1);
      a2 = fmaf(w[k + 2], buf[s + 16 * (k + 2)], a2);
      a3 = fmaf(w[k + 3], buf[s + 16 * (k + 3)], a3);
    }
    float sum = (a0 + a1) + (a2 + a3);
#pragma unroll
    for (int off = 1; off < 16; off <<= 1)
      sum += __shfl_xor(sum, off, 64);

    if (s == 0) {
      const float y = tanh_fast(sum + drv);
      // agent store: coherent-point write (cross-XCD safe, proven r2)
      __hip_atomic_store(&hexch[(size_t)t * HID + row], __float_as_uint(y),
                         __ATOMIC_RELAXED, __HIP_MEMORY_SCOPE_AGENT);
    }
  }
}

__global__ void copy_final(const float* __restrict__ src, float* __restrict__ dst) {
  dst[threadIdx.x] = src[threadIdx.x];
}

extern "C" void kernel_launch(void* const* d_in, const int* in_sizes, int n_in,
                              void* d_out, int out_size, void* d_ws, size_t ws_size,
                              hipStream_t stream) {
  const float* input    = (const float*)d_in[0];
  const float* internal = (const float*)d_in[1];
  const float* state    = (const float*)d_in[2];
  const float* W_ih     = (const float*)d_in[3];
  const float* W_hh     = (const float*)d_in[4];
  const float* bias     = (const float*)d_in[5];
  float* out = (float*)d_out;

  const size_t plane = (size_t)SEQ * HID;
  // hexch IS out plane 0 (hs): prefilled with sentinel, every element
  // overwritten exactly once by the recurrence.
  unsigned* hexch = (unsigned*)out;
  float*    drive = out + 5 * plane;   // rewritten by theta-GEMM k=4 afterwards

  fill_sentinel<<<(SEQ * HID / 4 + 255) / 256, 256, 0, stream>>>(
      (uint4*)hexch, SEQ * HID / 4);

  dim3 gg(HID / 64, SEQ / 64);
  // drive = x @ W_ih^T + b + internal[0]   (no tanh)
  gemm_bias_noise<<<gg, 256, 0, stream>>>(input, W_ih, bias, internal, drive,
                                          HID, 0);
  // hs (out plane 0, via sentinel exchange)
  recurrence<<<NBLK, 1024, 0, stream>>>(W_hh, drive, state, hexch);
  // theta rollouts: plane k -> plane k+1
  for (int k = 0; k < NTHETA; ++k) {
    gemm_bias_noise<<<gg, 256, 0, stream>>>(out + (size_t)k * plane, W_hh, bias,
                                            internal + (size_t)(k + 1) * plane,
                                            out + (size_t)(k + 1) * plane,
                                            HID, 1);
  }
  // final_state = hs[4095]
  copy_final<<<1, HID, 0, stream>>>(out + (size_t)4095 * HID, out + 6 * plane);
}

// Round 7
// 7490.240 us; speedup vs baseline: 1.5373x; 1.1805x over previous
//
#include <hip/hip_runtime.h>
#include <cstdint>
#include <cstddef>

#define SEQ 4096
#define HID 512
#define NTHETA 5
#define NBLK 8
#define SENT_BITS 0x40000000u   // 2.0f — |tanh| < 1, so never a real h value

typedef unsigned long long u64;

__device__ __forceinline__ float tanh_fast(float x) {
  x = fminf(fmaxf(x, -20.0f), 20.0f);
  const float e = __expf(2.0f * x);
  return (e - 1.0f) / (e + 1.0f);
}

// Butterfly sum over the 16-lane j-group: xor1/xor2 on the VALU (DPP
// quad_perm — keeps them OFF the DS pipe), xor4/xor8 via ds_swizzle.
__device__ __forceinline__ float red16(float v) {
  int p;
  p = __builtin_amdgcn_update_dpp(0, __float_as_int(v), 0xB1, 0xF, 0xF, true); // lane^1
  v += __int_as_float(p);
  p = __builtin_amdgcn_update_dpp(0, __float_as_int(v), 0x4E, 0xF, 0xF, true); // lane^2
  v += __int_as_float(p);
  v += __int_as_float(__builtin_amdgcn_ds_swizzle(__float_as_int(v), 0x101F)); // ^4
  v += __int_as_float(__builtin_amdgcn_ds_swizzle(__float_as_int(v), 0x201F)); // ^8
  return v;
}

// f4-chunk swizzle: logical f4 chunk f -> LDS slot z (2-way max on b128 reads)
__device__ __forceinline__ int swz(int f) {
  return (f & ~7) | ((f ^ (f >> 3)) & 7);
}

// C[4096,512] = act(A[4096,K] @ W[512,K]^T + bias + noise_plane)
__global__ __launch_bounds__(256) void gemm_bias_noise(
    const float* __restrict__ A, const float* __restrict__ W,
    const float* __restrict__ bias, const float* __restrict__ noise,
    float* __restrict__ C, int K, int doTanh)
{
  const int N = HID;
  const int bm = blockIdx.y, bn = blockIdx.x;
  const int tid = threadIdx.x;
  const int tx = tid & 15, ty = tid >> 4;
  const int row0 = bm * 64, col0 = bn * 64;
  __shared__ float As[16][68];
  __shared__ float Ws[16][68];
  float acc[4][4] = {{0.f, 0.f, 0.f, 0.f}, {0.f, 0.f, 0.f, 0.f},
                     {0.f, 0.f, 0.f, 0.f}, {0.f, 0.f, 0.f, 0.f}};
  const int lrow = tid >> 2, lkq = tid & 3;
  for (int kt = 0; kt < K; kt += 16) {
    const float4 av = *(const float4*)&A[(size_t)(row0 + lrow) * K + kt + lkq * 4];
    const float4 wv = *(const float4*)&W[(size_t)(col0 + lrow) * K + kt + lkq * 4];
    __syncthreads();
    As[lkq * 4 + 0][lrow] = av.x; As[lkq * 4 + 1][lrow] = av.y;
    As[lkq * 4 + 2][lrow] = av.z; As[lkq * 4 + 3][lrow] = av.w;
    Ws[lkq * 4 + 0][lrow] = wv.x; Ws[lkq * 4 + 1][lrow] = wv.y;
    Ws[lkq * 4 + 2][lrow] = wv.z; Ws[lkq * 4 + 3][lrow] = wv.w;
    __syncthreads();
#pragma unroll
    for (int k = 0; k < 16; ++k) {
      const float4 a = *(const float4*)&As[k][ty * 4];
      const float4 bq = *(const float4*)&Ws[k][tx * 4];
      const float a4[4] = {a.x, a.y, a.z, a.w};
      const float b4[4] = {bq.x, bq.y, bq.z, bq.w};
#pragma unroll
      for (int i = 0; i < 4; ++i)
#pragma unroll
        for (int j = 0; j < 4; ++j)
          acc[i][j] = fmaf(a4[i], b4[j], acc[i][j]);
    }
  }
  const float4 bv = *(const float4*)&bias[col0 + tx * 4];
#pragma unroll
  for (int i = 0; i < 4; ++i) {
    const int row = row0 + ty * 4 + i;
    const float4 nv = *(const float4*)&noise[(size_t)row * N + col0 + tx * 4];
    float4 o;
    o.x = acc[i][0] + bv.x + nv.x;
    o.y = acc[i][1] + bv.y + nv.y;
    o.z = acc[i][2] + bv.z + nv.z;
    o.w = acc[i][3] + bv.w + nv.w;
    if (doTanh) {
      o.x = tanh_fast(o.x); o.y = tanh_fast(o.y);
      o.z = tanh_fast(o.z); o.w = tanh_fast(o.w);
    }
    *(float4*)&C[(size_t)row * N + col0 + tx * 4] = o;
  }
}

// Pre-fill the h-exchange buffer (= out plane 0) with the sentinel bits.
__global__ void fill_sentinel(uint4* __restrict__ p, int n4) {
  const int i = blockIdx.x * blockDim.x + threadIdx.x;
  if (i < n4) p[i] = make_uint4(SENT_BITS, SENT_BITS, SENT_BITS, SENT_BITS);
}

// Sequential scan h_t = tanh(drive_t + W_hh @ h_{t-1}).
// 8 blocks x 256 thr (4 waves). Thread (i=tid>>4, j=tid&15) owns rows
// base+4i..+3 x cols 32j..+31: 128 W f32 values in VGPRs. Per step:
//   - u64 sentinel poll (224 pollers, 2 values each; own 64 values skipped)
//     into swizzled double-buffered LDS (ds_write_b64)
//   - 1 barrier
//   - 8 ds_read_b128 (<=2-way swizzled) feeding 128 FMAs (4x h-reuse)
//   - red16: DPP xor1/2 (VALU) + ds_swizzle xor4/8
//   - j==0: tanh x4, publish 4 agent b32 stores (= out plane 0 / hs),
//     and write own y4 straight into the NEXT LDS buffer (no 2nd barrier).
// DS-pipe cost/step ~72 instrs (vs 580 in r6, 190 in r2) — the new model's
// dominant removable term.
__global__ __launch_bounds__(256) void recurrence(
    const float* __restrict__ Whh, const float* __restrict__ drive,
    const float* __restrict__ h0, unsigned* __restrict__ hexch)
{
  const int blk = blockIdx.x;
  const int base = blk * 64;
  const int tid = threadIdx.x;
  const int i = tid >> 4;        // row-quad 0..15
  const int j = tid & 15;        // col-slice 0..15

  __shared__ float hbuf[2][HID];

  // W slice -> 128 f32 regs
  float4 wv0[8], wv1[8], wv2[8], wv3[8];
#pragma unroll
  for (int c = 0; c < 8; ++c) {
    const size_t rb = (size_t)(base + 4 * i) * HID + 32 * j + 4 * c;
    wv0[c] = *(const float4*)&Whh[rb];
    wv1[c] = *(const float4*)&Whh[rb + HID];
    wv2[c] = *(const float4*)&Whh[rb + 2 * HID];
    wv3[c] = *(const float4*)&Whh[rb + 3 * HID];
  }

  // poller mapping: floats 2*tid, 2*tid+1 -> swizzled LDS position
  const int fp = tid >> 1;
  const int woff = swz(fp) * 4 + (tid & 1) * 2;
  const bool own = (tid >= blk * 32) && (tid < blk * 32 + 32);

  // own-output slot (j==0 lanes): f4 chunk 16*blk + i
  const int zo = swz(16 * blk + i);

  for (int t = 0; t < SEQ; ++t) {
    const int buf = t & 1;

    float4 dv = make_float4(0.f, 0.f, 0.f, 0.f);
    if (j == 0)
      dv = *(const float4*)&drive[(size_t)t * HID + base + 4 * i];

    if (t == 0) {
      hbuf[0][woff]     = h0[2 * tid];
      hbuf[0][woff + 1] = h0[2 * tid + 1];
    } else if (!own) {
      const u64* src = (const u64*)&hexch[(size_t)(t - 1) * HID + 2 * tid];
      u64 u;
      do {
        u = __hip_atomic_load(src, __ATOMIC_RELAXED, __HIP_MEMORY_SCOPE_AGENT);
      } while ((unsigned)u == SENT_BITS || (unsigned)(u >> 32) == SENT_BITS);
      float2 hv;
      hv.x = __uint_as_float((unsigned)u);
      hv.y = __uint_as_float((unsigned)(u >> 32));
      *(float2*)&hbuf[buf][woff] = hv;
    }
    __syncthreads();
    // anchor dv here: its load issued pre-poll, forced resident before FMA
    asm volatile("" :: "v"(dv.x), "v"(dv.y), "v"(dv.z), "v"(dv.w));

    float a0 = 0.f, a1 = 0.f, a2 = 0.f, a3 = 0.f;
#pragma unroll
    for (int c = 0; c < 8; ++c) {
      const float4 h4 = *(const float4*)&hbuf[buf][(8 * j + ((c ^ j) & 7)) * 4];
      a0 = fmaf(wv0[c].x, h4.x, a0); a0 = fmaf(wv0[c].y, h4.y, a0);
      a0 = fmaf(wv0[c].z, h4.z, a0); a0 = fmaf(wv0[c].w, h4.w, a0);
      a1 = fmaf(wv1[c].x, h4.x, a1); a1 = fmaf(wv1[c].y, h4.y, a1);
      a1 = fmaf(wv1[c].z, h4.z, a1); a1 = fmaf(wv1[c].w, h4.w, a1);
      a2 = fmaf(wv2[c].x, h4.x, a2); a2 = fmaf(wv2[c].y, h4.y, a2);
      a2 = fmaf(wv2[c].z, h4.z, a2); a2 = fmaf(wv2[c].w, h4.w, a2);
      a3 = fmaf(wv3[c].x, h4.x, a3); a3 = fmaf(wv3[c].y, h4.y, a3);
      a3 = fmaf(wv3[c].z, h4.z, a3); a3 = fmaf(wv3[c].w, h4.w, a3);
    }
    a0 = red16(a0); a1 = red16(a1); a2 = red16(a2); a3 = red16(a3);

    if (j == 0) {
      const float y0 = tanh_fast(a0 + dv.x);
      const float y1 = tanh_fast(a1 + dv.y);
      const float y2 = tanh_fast(a2 + dv.z);
      const float y3 = tanh_fast(a3 + dv.w);
      unsigned* dst = &hexch[(size_t)t * HID + base + 4 * i];
      __hip_atomic_store(dst + 0, __float_as_uint(y0), __ATOMIC_RELAXED,
                         __HIP_MEMORY_SCOPE_AGENT);
      __hip_atomic_store(dst + 1, __float_as_uint(y1), __ATOMIC_RELAXED,
                         __HIP_MEMORY_SCOPE_AGENT);
      __hip_atomic_store(dst + 2, __float_as_uint(y2), __ATOMIC_RELAXED,
                         __HIP_MEMORY_SCOPE_AGENT);
      __hip_atomic_store(dst + 3, __float_as_uint(y3), __ATOMIC_RELAXED,
                         __HIP_MEMORY_SCOPE_AGENT);
      // own values never leave the CU: write straight into next buffer.
      // Safe: buf^1 was last read in step t-1 (all threads passed this
      // step's barrier => done with it); pollers at t+1 write disjoint slots.
      *(float4*)&hbuf[buf ^ 1][zo * 4] = make_float4(y0, y1, y2, y3);
    }
  }
}

__global__ void copy_final(const float* __restrict__ src, float* __restrict__ dst) {
  dst[threadIdx.x] = src[threadIdx.x];
}

extern "C" void kernel_launch(void* const* d_in, const int* in_sizes, int n_in,
                              void* d_out, int out_size, void* d_ws, size_t ws_size,
                              hipStream_t stream) {
  const float* input    = (const float*)d_in[0];
  const float* internal = (const float*)d_in[1];
  const float* state    = (const float*)d_in[2];
  const float* W_ih     = (const float*)d_in[3];
  const float* W_hh     = (const float*)d_in[4];
  const float* bias     = (const float*)d_in[5];
  float* out = (float*)d_out;

  const size_t plane = (size_t)SEQ * HID;
  // hexch IS out plane 0 (hs): prefilled with sentinel, every element
  // overwritten exactly once by the recurrence.
  unsigned* hexch = (unsigned*)out;
  float*    drive = out + 5 * plane;   // rewritten by theta-GEMM k=4 afterwards

  fill_sentinel<<<(SEQ * HID / 4 + 255) / 256, 256, 0, stream>>>(
      (uint4*)hexch, SEQ * HID / 4);

  dim3 gg(HID / 64, SEQ / 64);
  // drive = x @ W_ih^T + b + internal[0]   (no tanh)
  gemm_bias_noise<<<gg, 256, 0, stream>>>(input, W_ih, bias, internal, drive,
                                          HID, 0);
  // hs (out plane 0, via sentinel exchange)
  recurrence<<<NBLK, 256, 0, stream>>>(W_hh, drive, state, hexch);
  // theta rollouts: plane k -> plane k+1
  for (int k = 0; k < NTHETA; ++k) {
    gemm_bias_noise<<<gg, 256, 0, stream>>>(out + (size_t)k * plane, W_hh, bias,
                                            internal + (size_t)(k + 1) * plane,
                                            out + (size_t)(k + 1) * plane,
                                            HID, 1);
  }
  // final_state = hs[4095]
  copy_final<<<1, HID, 0, stream>>>(out + (size_t)4095 * HID, out + 6 * plane);
}